// Round 1
// 62.357 us; speedup vs baseline: 1.0019x; 1.0019x over previous
//
#include <hip/hip_runtime.h>

// MeshNN: u(x) = sum_j w_uu[j]*hat_j(x) + w_dd[0]*phi_0(x) + w_dd[1]*phi_L(x)
// Hats have compact support (c[j], c[j+2]): only 2 interior hats + 2 boundary
// hats are nonzero per point -> O(1) work/point. Memory: 2 MB in + 2 MB out.
//
// R3: 4 points/thread via float4 (16 B/lane), 489 blocks instead of 1954 so
// the per-block LDS table build is amortized 4x; X load issued BEFORE the
// table build so its HBM latency hides under setup; first __syncthreads
// removed (each thread loads its own 3 neighbor coords from global, which is
// L1/L2-resident after the first block).

#define TPf ((float)(1.0 - 1.0 / 150.0))
#define TMf ((float)(1.0 + 1.0 / 150.0))

__device__ __forceinline__ float hat_rcp(float x, float xm, float xi, float xp,
                                         float rl, float rr) {
    // left  = relu(relu(xi - x) * (-1/(xi - xm)) + 1)   with rl = 1/(xi - xm)
    // right = relu(relu(x - xi) * (-1/(xp - xi)) + 1)   with rr = 1/(xp - xi)
    float l = fmaxf(fmaxf(xi - x, 0.0f) * (-rl) + 1.0f, 0.0f);
    float r = fmaxf(fmaxf(x - xi, 0.0f) * (-rr) + 1.0f, 0.0f);
    return l + r - 1.0f;
}

__global__ __launch_bounds__(256) void MeshNN_29042568855825_kernel(
    const float* __restrict__ X,   // (n,)
    const float* __restrict__ C,   // (258,)
    const float* __restrict__ Wu,  // (256,)
    const float* __restrict__ Wd,  // (2,)
    float* __restrict__ Out,       // (n,)
    int n)
{
    __shared__ float sc[258];   // node coordinates
    __shared__ float sxi[256];  // clamped center of interior hat j
    __shared__ float srl[256];  // 1/(xi - xm) for interior hat j
    __shared__ float srr[256];  // 1/(xp - xi) for interior hat j
    __shared__ float sw[256];   // w_uu
    __shared__ float sb[12];    // boundary consts

    const int tid  = threadIdx.x;
    const int base = (blockIdx.x * 256 + tid) * 4;

    // ---- 1) issue the streaming X load FIRST: its ~900-cycle HBM latency
    // hides under the independent table-build below.
    float x0 = 0.f, x1 = 0.f, x2 = 0.f, x3 = 0.f;
    const bool full = (base + 4 <= n);
    if (full) {
        const float4 xv = *reinterpret_cast<const float4*>(X + base);
        x0 = xv.x; x1 = xv.y; x2 = xv.z; x3 = xv.w;
    } else if (base < n) {
        x0 = X[base];
        if (base + 1 < n) x1 = X[base + 1];
        if (base + 2 < n) x2 = X[base + 2];
        if (base + 3 < n) x3 = X[base + 3];
    }

    // ---- 2) per-node tables with NO pre-barrier: each thread pulls its own
    // 3 neighbor coords straight from global (C is 1 KB, cache-resident).
    {
        const int j = tid;  // interior hat j: xm=c[j], xi=c[j+1] clamped, xp=c[j+2]
        const float xm = C[j], xr = C[j + 1], xp = C[j + 2];
        sc[j] = xm;
        if (j == 255) { sc[256] = xr; sc[257] = xp; }
        const float xic = fmaxf(fminf(xr, TPf * xp), TMf * xm);
        sxi[j] = xic;
        srl[j] = 1.0f / (xic - xm);
        srr[j] = 1.0f / (xp - xic);
        sw[j]  = Wu[j];
    }
    if (tid == 0) {
        const float c0 = C[0], c1 = C[1], cNm2 = C[256], cNm1 = C[257];
        const float xm0 = c0 - cNm1 / 100.0f;                 // c[0] - c[-1]/100
        const float xi0 = fmaxf(fminf(c0, TPf * c1), TMf * xm0);
        const float xpL = cNm1 * (float)(1.0 + 1.0 / 100.0);  // c[-1]*1.01
        const float xiL = fmaxf(fminf(cNm1, TPf * xpL), TMf * cNm2);
        sb[0] = xm0;  sb[1] = xi0;  sb[2] = c1;
        sb[3] = 1.0f / (xi0 - xm0); sb[4] = 1.0f / (c1 - xi0);
        sb[5] = cNm2; sb[6] = xiL;  sb[7] = xpL;
        sb[8] = 1.0f / (xiL - cNm2); sb[9] = 1.0f / (xpL - xiL);
        sb[10] = Wd[0]; sb[11] = Wd[1];
    }
    __syncthreads();

    if (base >= n) return;

    const float c0    = sc[0];
    const float inv_h = 257.0f / (sc[257] - c0);

    // boundary consts to registers once (reused for all 4 points)
    const float bm0 = sb[0], bi0 = sb[1], bp0 = sb[2], brl0 = sb[3], brr0 = sb[4];
    const float bmL = sb[5], biL = sb[6], bpL = sb[7], brlL = sb[8], brrL = sb[9];
    const float wd0 = sb[10], wdL = sb[11];

    const float xs[4] = {x0, x1, x2, x3};
    float out[4];

    #pragma unroll
    for (int k = 0; k < 4; ++k) {
        const float x = xs[k];

        // locate interval i : sc[i] <= x < sc[i+1]  (guess exact for linspace)
        int i = (int)((x - c0) * inv_h);
        i = min(max(i, 0), 256);
        while (i > 0 && x < sc[i]) --i;
        while (i < 256 && x >= sc[i + 1]) ++i;

        // boundary hats (exact zero away from edges, always cheap)
        float u = wd0 * hat_rcp(x, bm0, bi0, bp0, brl0, brr0)
                + wdL * hat_rcp(x, bmL, biL, bpL, brlL, brrL);

        // interior hat j = i-1: support (c[i-1], c[i+1])
        if (i >= 1) {
            const int j = i - 1;
            u += sw[j] * hat_rcp(x, sc[j], sxi[j], sc[j + 2], srl[j], srr[j]);
        }
        // interior hat j = i: support (c[i], c[i+2])
        if (i <= 255) {
            const int j = i;
            u += sw[j] * hat_rcp(x, sc[j], sxi[j], sc[j + 2], srl[j], srr[j]);
        }
        out[k] = u;
    }

    if (full) {
        *reinterpret_cast<float4*>(Out + base) =
            make_float4(out[0], out[1], out[2], out[3]);
    } else {
        for (int k = 0; k < 4 && base + k < n; ++k) Out[base + k] = out[k];
    }
}

extern "C" void kernel_launch(void* const* d_in, const int* in_sizes, int n_in,
                              void* d_out, int out_size, void* d_ws, size_t ws_size,
                              hipStream_t stream) {
    const float* x  = (const float*)d_in[0];   // (500000,1) fp32
    const float* c  = (const float*)d_in[1];   // (258,)     fp32
    const float* wu = (const float*)d_in[2];   // (256,)     fp32
    const float* wd = (const float*)d_in[3];   // (2,)       fp32
    float* out = (float*)d_out;                // (500000,1) fp32

    const int n = in_sizes[0];
    int blocks = (n + 1023) / 1024;
    if (blocks < 1) blocks = 1;
    MeshNN_29042568855825_kernel<<<blocks, 256, 0, stream>>>(x, c, wu, wd, out, n);
}